// Round 17
// baseline (263.292 us; speedup 1.0000x reference)
//
#include <hip/hip_runtime.h>

typedef _Float16 half8 __attribute__((ext_vector_type(8)));
typedef _Float16 half4 __attribute__((ext_vector_type(4)));
typedef float floatx4 __attribute__((ext_vector_type(4)));
typedef float floatx16 __attribute__((ext_vector_type(16)));

#define MFMA16(A,B,C) __builtin_amdgcn_mfma_f32_16x16x32_f16((A),(B),(C),0,0,0)
#define MFMA32(A,B,C) __builtin_amdgcn_mfma_f32_32x32x16_f16((A),(B),(C),0,0,0)

// Problem constants (B=4, S=2048, D=1024, H=16, DPH=64)

// ---------------------------------------------------------------------------
// K0: bit-pack the int32 bool mask [B,S,S] -> u32 words, TRANSPOSED layout
// p[(b*64 + w)*2048 + s] = bits for row s, keys [w*32, w*32+32).
// ---------------------------------------------------------------------------
__global__ __launch_bounds__(256) void maskpack(
    const int* __restrict__ m, unsigned int* __restrict__ p)
{
  const int w = blockIdx.x * 256 + threadIdx.x;   // 524288 words total
  const int b = w >> 17;
  const int rem = w & 131071;
  const int s = rem >> 6;
  const int wp = rem & 63;
  const int4* src = (const int4*)(m + (size_t)w * 32);
  unsigned int bits = 0;
#pragma unroll
  for (int j = 0; j < 8; ++j) {
    const int4 v = src[j];
    bits |= (v.x ? 1u : 0u) << (j * 4 + 0);
    bits |= (v.y ? 1u : 0u) << (j * 4 + 1);
    bits |= (v.z ? 1u : 0u) << (j * 4 + 2);
    bits |= (v.w ? 1u : 0u) << (j * 4 + 3);
  }
  p[((size_t)(b * 64 + wp)) * 2048 + s] = bits;
}

// ---------------------------------------------------------------------------
// K1: convert the 4 weight matrices fp32 [k][n] -> fp16 W^T [n][k]
// ---------------------------------------------------------------------------
__global__ __launch_bounds__(256) void wconv(
    const float* __restrict__ Wq, const float* __restrict__ Wk,
    const float* __restrict__ Wv, const float* __restrict__ Wo,
    _Float16* __restrict__ dst)
{
  const float* W = (blockIdx.z == 0) ? Wq : (blockIdx.z == 1) ? Wk
                  : (blockIdx.z == 2) ? Wv : Wo;
  _Float16* WT = dst + (size_t)blockIdx.z * 1024 * 1024;
  __shared__ float t[32][33];
  const int tx = threadIdx.x & 31;
  const int ty = threadIdx.x >> 5;
  const int k0 = blockIdx.x * 32, n0 = blockIdx.y * 32;
#pragma unroll
  for (int j = 0; j < 4; ++j)
    t[ty + j * 8][tx] = W[(size_t)(k0 + ty + j * 8) * 1024 + n0 + tx];
  __syncthreads();
#pragma unroll
  for (int j = 0; j < 4; ++j)
    WT[(size_t)(n0 + ty + j * 8) * 1024 + k0 + tx] = (_Float16)t[tx][ty + j * 8];
}

// ---------------------------------------------------------------------------
// K2/K4: GEMM C[8192,1024] = A[8192,1024] @ W + bias, fp16 MFMA, fp32 accum.
// Tile 128(M) x 256(N), BK=64, 8 waves (wave = 64x64 quadrant, acc[4][4]).
// BN=256 halves A's per-FLOP L2 traffic (A fp32 staged once per 2 n-tiles
// worth of output instead of per 1) and halves B HBM re-reads. Grid 256
// blocks = 1/CU. Swizzled LDS, reg-staged A w/ packed cvt (r13 math).
// OP 0: A=query fp32, out = half q_up [B,H,S,64], (acc+bias)*0.125*log2(e)
// OP 1: A=key   fp32, out = half k_up [B,H,S,64]
// OP 2: A=value fp32, out = half vT   [B,H,64,S], KEY INDEX BITS 2<->3
//       SWAPPED (k-axis permutation so attn's PV B-frags need no exchange)
// OP 3: A=ctx  fp16,  out = float d_out [8192,1024]
// ---------------------------------------------------------------------------
template <int OP>
__global__ __launch_bounds__(512) void gemm_k(
    const void* __restrict__ Ap, const _Float16* __restrict__ BT,
    const float* __restrict__ bias, void* __restrict__ Cp)
{
  __shared__ __align__(16) _Float16 As[128 * 64];   // 16 KB
  __shared__ __align__(16) _Float16 Bs[256 * 64];   // 32 KB
  const int tid = threadIdx.x;
  const int lane = tid & 63;
  const int wv = tid >> 6;               // 0..7
  const int m0 = blockIdx.x * 128;
  const int n0 = blockIdx.y * 256;
  const int wr = (wv >> 2) * 64;         // 0,64
  const int wc = (wv & 3) * 64;          // 0,64,128,192

  floatx4 acc[4][4];
#pragma unroll
  for (int i = 0; i < 4; ++i)
#pragma unroll
    for (int j = 0; j < 4; ++j) acc[i][j] = (floatx4){0.f, 0.f, 0.f, 0.f};

  char* AsB = (char*)As;
  char* BsB = (char*)Bs;

  for (int ko = 0; ko < 1024; ko += 64) {
    // stage A: 128x64 halfs (2 chunks of 512 thr x 8 halfs)
#pragma unroll
    for (int r = 0; r < 2; ++r) {
      const int idx = (r * 512 + tid) * 8;
      const int row = idx >> 6;
      const int colh = idx & 63;
      const int dstb = row * 128 + ((colh * 2) ^ ((row & 7) << 4));
      if (OP == 3) {
        const _Float16* s = (const _Float16*)Ap + (size_t)(m0 + row) * 1024 + ko + colh;
        *(half8*)(AsB + dstb) = *(const half8*)s;
      } else {
        const float* s = (const float*)Ap + (size_t)(m0 + row) * 1024 + ko + colh;
        floatx4 v0 = *(const floatx4*)s;
        floatx4 v1 = *(const floatx4*)(s + 4);
        union { half8 v; unsigned int u[4]; } pk;
        pk.u[0] = __builtin_bit_cast(unsigned int, __builtin_amdgcn_cvt_pkrtz(v0[0], v0[1]));
        pk.u[1] = __builtin_bit_cast(unsigned int, __builtin_amdgcn_cvt_pkrtz(v0[2], v0[3]));
        pk.u[2] = __builtin_bit_cast(unsigned int, __builtin_amdgcn_cvt_pkrtz(v1[0], v1[1]));
        pk.u[3] = __builtin_bit_cast(unsigned int, __builtin_amdgcn_cvt_pkrtz(v1[2], v1[3]));
        *(half8*)(AsB + dstb) = pk.v;
      }
    }
    // stage B: 256x64 halfs (4 chunks)
#pragma unroll
    for (int r = 0; r < 4; ++r) {
      const int idx = (r * 512 + tid) * 8;
      const int row = idx >> 6;
      const int colh = idx & 63;
      const int dstb = row * 128 + ((colh * 2) ^ ((row & 7) << 4));
      const _Float16* bs = BT + (size_t)(n0 + row) * 1024 + ko + colh;
      *(half8*)(BsB + dstb) = *(const half8*)bs;
    }
    __syncthreads();
#pragma unroll
    for (int kk = 0; kk < 64; kk += 32) {
      half8 af[4], bf[4];
#pragma unroll
      for (int mi = 0; mi < 4; ++mi) {
        const int row = wr + mi * 16 + (lane & 15);
        const int cb = (kk + (lane >> 4) * 8) * 2;
        af[mi] = *(const half8*)(AsB + row * 128 + (cb ^ ((row & 7) << 4)));
      }
#pragma unroll
      for (int ni = 0; ni < 4; ++ni) {
        const int row = wc + ni * 16 + (lane & 15);
        const int cb = (kk + (lane >> 4) * 8) * 2;
        bf[ni] = *(const half8*)(BsB + row * 128 + (cb ^ ((row & 7) << 4)));
      }
#pragma unroll
      for (int mi = 0; mi < 4; ++mi)
#pragma unroll
        for (int ni = 0; ni < 4; ++ni)
          acc[mi][ni] = MFMA16(af[mi], bf[ni], acc[mi][ni]);
    }
    __syncthreads();
  }

  // Epilogue. C/D layout: col = lane&15, row = (lane>>4)*4 + i
#pragma unroll
  for (int ni = 0; ni < 4; ++ni) {
    const int nn = n0 + wc + ni * 16 + (lane & 15);
    const float bvv = bias[nn];
#pragma unroll
    for (int mi = 0; mi < 4; ++mi) {
      floatx4 c = acc[mi][ni];
#pragma unroll
      for (int i = 0; i < 4; ++i) {
        const int mm = m0 + wr + mi * 16 + (lane >> 4) * 4 + i;
        float val = c[i] + bvv;
        if (OP == 0) val *= 0.1803368801111204f;   // (1/8) * log2(e)
        if (OP == 0 || OP == 1) {
          _Float16* o = (_Float16*)Cp;
          const size_t off =
              ((size_t)((mm >> 11) * 16 + (nn >> 6)) * 2048 + (mm & 2047)) * 64 + (nn & 63);
          o[off] = (_Float16)val;
        } else if (OP == 2) {
          _Float16* o = (_Float16*)Cp;
          // key index with bits 2<->3 swapped (k-axis permutation for PV)
          const int mmp = (mm & ~0xC) | ((mm & 4) << 1) | ((mm & 8) >> 1);
          const size_t off =
              ((size_t)((mm >> 11) * 16 + (nn >> 6)) * 64 + (nn & 63)) * 2048 + (mmp & 2047);
          o[off] = (_Float16)val;
        } else {
          float* o = (float*)Cp;
          o[(size_t)mm * 1024 + nn] = val;
        }
      }
    }
  }
}

// ---------------------------------------------------------------------------
// K3: flash attention, 32x32x16 MFMA, fixed-max in-register softmax.
// (unchanged from round 15 — 97 us; 8 waves/block, 1 q-tile/wave,
// fixed-max log2 softmax, k-permuted PV, K/V LDS double-buffer)
// ---------------------------------------------------------------------------
__global__ __launch_bounds__(512) void attn_k(
    const _Float16* __restrict__ q_up, const _Float16* __restrict__ k_up,
    const _Float16* __restrict__ vT, const unsigned int* __restrict__ pmaskT,
    _Float16* __restrict__ ctx)
{
  const int tid = threadIdx.x;
  const int lane = tid & 63;
  const int wv = tid >> 6;                 // 0..7
  const int bid = blockIdx.x;
  const int xcd = bid & 7;
  const int slot = bid >> 3;
  const int bh = xcd * 8 + (slot & 7);
  const int qc = slot >> 3;
  const int b = bh >> 4;
  const int h = bh & 15;
  const int l31 = lane & 31;
  const int hi = lane >> 5;
  const int qw = qc * 256 + wv * 32;       // wave's 32 q-rows

  __shared__ __align__(16) _Float16 Kl[2][32 * 64];   // 2 x 4KB
  __shared__ __align__(16) _Float16 Vl[2][64 * 32];   // 2 x 4KB

  const _Float16* qb = q_up + ((size_t)bh * 2048 + qw) * 64;
  const _Float16* kb = k_up + (size_t)bh * 2048 * 64;
  const _Float16* vb = vT + (size_t)bh * 64 * 2048;
  const unsigned int* mbase = pmaskT + (size_t)(b * 64) * 2048 + qw + l31;

  // staging: waves 0-3 stage K (256 thr x 16B = 4KB), waves 4-7 stage V.
  const bool isK = tid < 256;
  const int st = isK ? tid : tid - 256;
  const int krow = st >> 3, kseg = st & 7;
  const int vrow = st >> 2, vseg = st & 3;
  const int sOff = isK ? (krow * 128 + ((kseg * 16) ^ ((krow & 7) << 4)))
                       : (vrow * 64 + ((vseg * 16) ^ (((vrow >> 1) & 3) << 4)));
  const _Float16* gsrc = isK ? (kb + (size_t)st * 8)
                             : (vb + (size_t)vrow * 2048 + vseg * 8);
  const int gstride = isK ? 2048 : 32;     // halfs per 32-key tile
  char* Lbase = isK ? (char*)Kl : (char*)Vl;
  char* KB = (char*)Kl;
  char* VB = (char*)Vl;

  // Q B-frags (hoisted): col=q=l31, k = kk*16 + hi*8 + j
  half8 qf[4];
#pragma unroll
  for (int kk = 0; kk < 4; ++kk)
    qf[kk] = *(const half8*)(qb + (size_t)l31 * 64 + kk * 16 + hi * 8);

  floatx16 O[2];
#pragma unroll
  for (int dt = 0; dt < 2; ++dt)
#pragma unroll
    for (int r = 0; r < 16; ++r) O[dt][r] = 0.f;
  float lsum = 0.f;

  floatx16 zero16;
#pragma unroll
  for (int r = 0; r < 16; ++r) zero16[r] = 0.f;

  half8 stg;

  auto COMPUTE = [&](int buf, int t) {
    const unsigned int mw = mbase[(size_t)t * 2048];
    half8 kf[4];
#pragma unroll
    for (int kk = 0; kk < 4; ++kk)
      kf[kk] = *(const half8*)(KB + buf * 4096 + l31 * 128 +
                               ((kk * 32 + hi * 16) ^ ((l31 & 7) << 4)));
    half8 vf[2][2];
#pragma unroll
    for (int dt = 0; dt < 2; ++dt)
#pragma unroll
      for (int kk2 = 0; kk2 < 2; ++kk2)
        vf[dt][kk2] = *(const half8*)(VB + buf * 4096 + (dt * 32 + l31) * 64 +
                                      ((kk2 * 32 + hi * 16) ^ (((l31 >> 1) & 3) << 4)));

    floatx16 s;
    __builtin_amdgcn_s_setprio(1);
    {
      floatx16 a;
      a = MFMA32(kf[0], qf[0], zero16);
      a = MFMA32(kf[1], qf[1], a);
      a = MFMA32(kf[2], qf[2], a);
      s = MFMA32(kf[3], qf[3], a);
    }
    __builtin_amdgcn_s_setprio(0);

    const unsigned int mh = mw >> (4 * hi);
    float e[16];
#pragma unroll
    for (int m = 0; m < 4; ++m) {
      const unsigned int bm = mh >> (8 * m);
#pragma unroll
      for (int j = 0; j < 4; ++j)
        e[4 * m + j] = ((bm >> j) & 1u) ? 0.f : __builtin_amdgcn_exp2f(s[4 * m + j]);
    }
    float u0 = (e[0] + e[1]) + (e[2] + e[3]);
    float u1 = (e[4] + e[5]) + (e[6] + e[7]);
    float u2 = (e[8] + e[9]) + (e[10] + e[11]);
    float u3 = (e[12] + e[13]) + (e[14] + e[15]);
    lsum += (u0 + u1) + (u2 + u3);

    union { half8 v; unsigned int u[4]; } p0, p1;
    p0.u[0] = __builtin_bit_cast(unsigned int, __builtin_amdgcn_cvt_pkrtz(e[0], e[1]));
    p0.u[1] = __builtin_bit_cast(unsigned int, __builtin_amdgcn_cvt_pkrtz(e[2], e[3]));
    p0.u[2] = __builtin_bit_cast(unsigned int, __builtin_amdgcn_cvt_pkrtz(e[4], e[5]));
    p0.u[3] = __builtin_bit_cast(unsigned int, __builtin_amdgcn_cvt_pkrtz(e[6], e[7]));
    p1.u[0] = __builtin_bit_cast(unsigned int, __builtin_amdgcn_cvt_pkrtz(e[8], e[9]));
    p1.u[1] = __builtin_bit_cast(unsigned int, __builtin_amdgcn_cvt_pkrtz(e[10], e[11]));
    p1.u[2] = __builtin_bit_cast(unsigned int, __builtin_amdgcn_cvt_pkrtz(e[12], e[13]));
    p1.u[3] = __builtin_bit_cast(unsigned int, __builtin_amdgcn_cvt_pkrtz(e[14], e[15]));
    __builtin_amdgcn_s_setprio(1);
#pragma unroll
    for (int dt = 0; dt < 2; ++dt) {
      O[dt] = MFMA32(vf[dt][0], p0.v, O[dt]);
      O[dt] = MFMA32(vf[dt][1], p1.v, O[dt]);
    }
    __builtin_amdgcn_s_setprio(0);
  };

  // prologue: stage tile 0 into buf0; fetch tile 1 into regs
  stg = *(const half8*)gsrc;
  *(half8*)(Lbase + sOff) = stg;
  stg = *(const half8*)(gsrc + gstride);
  __syncthreads();

#pragma unroll 1
  for (int t = 0; t < 64; t += 2) {
    {
      *(half8*)(Lbase + 4096 + sOff) = stg;
      const int tn = (t + 2 < 64) ? t + 2 : 0;
      stg = *(const half8*)(gsrc + (size_t)tn * gstride);
      COMPUTE(0, t);
      __syncthreads();
    }
    {
      *(half8*)(Lbase + sOff) = stg;
      const int tn = (t + 3 < 64) ? t + 3 : 0;
      stg = *(const half8*)(gsrc + (size_t)tn * gstride);
      COMPUTE(1, t + 1);
      __syncthreads();
    }
  }

  // Epilogue: cross-half lsum combine, then O^T write.
  {
    const float tot = lsum + __shfl_xor(lsum, 32);
    const float inv = 1.f / tot;
    const size_t rowb = ((size_t)(b * 2048 + qw + l31)) * 1024 + h * 64;
#pragma unroll
    for (int dt = 0; dt < 2; ++dt) {
#pragma unroll
      for (int m = 0; m < 4; ++m) {
        half4 w4;
        w4[0] = (_Float16)(O[dt][4 * m + 0] * inv);
        w4[1] = (_Float16)(O[dt][4 * m + 1] * inv);
        w4[2] = (_Float16)(O[dt][4 * m + 2] * inv);
        w4[3] = (_Float16)(O[dt][4 * m + 3] * inv);
        *(half4*)(ctx + rowb + dt * 32 + 8 * m + 4 * hi) = w4;
      }
    }
  }
}

// ---------------------------------------------------------------------------
// Launch. Workspace (fp16 elems): WT 4M | q_up 8M | k_up 8M | vT 8M | ctx 8M
// | pmaskT 2MB. Total ~74 MB.
// ---------------------------------------------------------------------------
extern "C" void kernel_launch(void* const* d_in, const int* in_sizes, int n_in,
                              void* d_out, int out_size, void* d_ws, size_t ws_size,
                              hipStream_t stream) {
  const float* key   = (const float*)d_in[0];
  const float* value = (const float*)d_in[1];
  const float* query = (const float*)d_in[2];
  const int*   mask  = (const int*)d_in[3];     // bool -> int32 per harness
  const float* Wq = (const float*)d_in[4];
  const float* bq = (const float*)d_in[5];
  const float* Wk = (const float*)d_in[6];
  const float* bk = (const float*)d_in[7];
  const float* Wv = (const float*)d_in[8];
  const float* bv = (const float*)d_in[9];
  const float* Wo = (const float*)d_in[10];
  const float* bo = (const float*)d_in[11];

  _Float16* wsp = (_Float16*)d_ws;
  _Float16* WT   = wsp;
  _Float16* q_up = wsp + (size_t)4 * 1024 * 1024;
  _Float16* k_up = q_up + (size_t)8192 * 1024;
  _Float16* vT   = k_up + (size_t)8192 * 1024;
  _Float16* ctx  = vT + (size_t)8192 * 1024;
  unsigned int* pmaskT = (unsigned int*)(ctx + (size_t)8192 * 1024);

  maskpack<<<dim3(2048), 256, 0, stream>>>(mask, pmaskT);
  wconv<<<dim3(32, 32, 4), 256, 0, stream>>>(Wq, Wk, Wv, Wo, WT);
  gemm_k<0><<<dim3(64, 4), 512, 0, stream>>>(query, WT, bq, q_up);
  gemm_k<1><<<dim3(64, 4), 512, 0, stream>>>(key, WT + (size_t)1024 * 1024, bk, k_up);
  gemm_k<2><<<dim3(64, 4), 512, 0, stream>>>(value, WT + (size_t)2 * 1024 * 1024, bv, vT);
  attn_k<<<dim3(512), 512, 0, stream>>>(q_up, k_up, vT, pmaskT, ctx);
  gemm_k<3><<<dim3(64, 4), 512, 0, stream>>>(ctx, WT + (size_t)3 * 1024 * 1024, bo, (float*)d_out);
}

// Round 18
// 251.988 us; speedup vs baseline: 1.0449x; 1.0449x over previous
//
#include <hip/hip_runtime.h>

typedef _Float16 half8 __attribute__((ext_vector_type(8)));
typedef _Float16 half4 __attribute__((ext_vector_type(4)));
typedef float floatx4 __attribute__((ext_vector_type(4)));
typedef float floatx16 __attribute__((ext_vector_type(16)));

#define MFMA16(A,B,C) __builtin_amdgcn_mfma_f32_16x16x32_f16((A),(B),(C),0,0,0)
#define MFMA32(A,B,C) __builtin_amdgcn_mfma_f32_32x32x16_f16((A),(B),(C),0,0,0)

// Problem constants (B=4, S=2048, D=1024, H=16, DPH=64)

// ---------------------------------------------------------------------------
// K0: bit-pack the int32 bool mask [B,S,S] -> u32 words, TRANSPOSED layout
// p[(b*64 + w)*2048 + s] = bits for row s, keys [w*32, w*32+32).
// ---------------------------------------------------------------------------
__global__ __launch_bounds__(256) void maskpack(
    const int* __restrict__ m, unsigned int* __restrict__ p)
{
  const int w = blockIdx.x * 256 + threadIdx.x;   // 524288 words total
  const int b = w >> 17;
  const int rem = w & 131071;
  const int s = rem >> 6;
  const int wp = rem & 63;
  const int4* src = (const int4*)(m + (size_t)w * 32);
  unsigned int bits = 0;
#pragma unroll
  for (int j = 0; j < 8; ++j) {
    const int4 v = src[j];
    bits |= (v.x ? 1u : 0u) << (j * 4 + 0);
    bits |= (v.y ? 1u : 0u) << (j * 4 + 1);
    bits |= (v.z ? 1u : 0u) << (j * 4 + 2);
    bits |= (v.w ? 1u : 0u) << (j * 4 + 3);
  }
  p[((size_t)(b * 64 + wp)) * 2048 + s] = bits;
}

// ---------------------------------------------------------------------------
// K1: convert the 4 weight matrices fp32 [k][n] -> fp16 W^T [n][k]
// ---------------------------------------------------------------------------
__global__ __launch_bounds__(256) void wconv(
    const float* __restrict__ Wq, const float* __restrict__ Wk,
    const float* __restrict__ Wv, const float* __restrict__ Wo,
    _Float16* __restrict__ dst)
{
  const float* W = (blockIdx.z == 0) ? Wq : (blockIdx.z == 1) ? Wk
                  : (blockIdx.z == 2) ? Wv : Wo;
  _Float16* WT = dst + (size_t)blockIdx.z * 1024 * 1024;
  __shared__ float t[32][33];
  const int tx = threadIdx.x & 31;
  const int ty = threadIdx.x >> 5;
  const int k0 = blockIdx.x * 32, n0 = blockIdx.y * 32;
#pragma unroll
  for (int j = 0; j < 4; ++j)
    t[ty + j * 8][tx] = W[(size_t)(k0 + ty + j * 8) * 1024 + n0 + tx];
  __syncthreads();
#pragma unroll
  for (int j = 0; j < 4; ++j)
    WT[(size_t)(n0 + ty + j * 8) * 1024 + k0 + tx] = (_Float16)t[tx][ty + j * 8];
}

// ---------------------------------------------------------------------------
// K2/K4: GEMM C[8192,1024] = A[8192,1024] @ W + bias, fp16 MFMA, fp32 accum.
// (r13/r15 form — the best measured; all 4 structural variants regressed)
// OP 0: A=query fp32, out = half q_up [B,H,S,64], (acc+bias)*0.125*log2(e)
// OP 1: A=key   fp32, out = half k_up [B,H,S,64]
// OP 2: A=value fp32, out = half vT   [B,H,64,S], KEY INDEX BITS 2<->3
//       SWAPPED (k-axis permutation so attn's PV B-frags need no exchange)
// OP 3: A=ctx  fp16,  out = float d_out [8192,1024]
// ---------------------------------------------------------------------------
template <int OP>
__global__ __launch_bounds__(256) void gemm_k(
    const void* __restrict__ Ap, const _Float16* __restrict__ BT,
    const float* __restrict__ bias, void* __restrict__ Cp)
{
  __shared__ __align__(16) _Float16 As[128 * 64];
  __shared__ __align__(16) _Float16 Bs[128 * 64];
  const int tid = threadIdx.x;
  const int lane = tid & 63;
  const int wv = tid >> 6;
  const int m0 = blockIdx.x * 128;
  const int n0 = blockIdx.y * 128;
  const int wr = (wv >> 1) * 64;
  const int wc = (wv & 1) * 64;

  floatx4 acc[4][4];
#pragma unroll
  for (int i = 0; i < 4; ++i)
#pragma unroll
    for (int j = 0; j < 4; ++j) acc[i][j] = (floatx4){0.f, 0.f, 0.f, 0.f};

  char* AsB = (char*)As;
  char* BsB = (char*)Bs;

  for (int ko = 0; ko < 1024; ko += 64) {
#pragma unroll
    for (int r = 0; r < 4; ++r) {
      const int idx = (r * 256 + tid) * 8;   // half index within 128x64 tile
      const int row = idx >> 6;
      const int colh = idx & 63;
      const int dstb = row * 128 + ((colh * 2) ^ ((row & 7) << 4));
      if (OP == 3) {
        const _Float16* s = (const _Float16*)Ap + (size_t)(m0 + row) * 1024 + ko + colh;
        *(half8*)(AsB + dstb) = *(const half8*)s;
      } else {
        const float* s = (const float*)Ap + (size_t)(m0 + row) * 1024 + ko + colh;
        floatx4 v0 = *(const floatx4*)s;
        floatx4 v1 = *(const floatx4*)(s + 4);
        union { half8 v; unsigned int u[4]; } pk;
        pk.u[0] = __builtin_bit_cast(unsigned int, __builtin_amdgcn_cvt_pkrtz(v0[0], v0[1]));
        pk.u[1] = __builtin_bit_cast(unsigned int, __builtin_amdgcn_cvt_pkrtz(v0[2], v0[3]));
        pk.u[2] = __builtin_bit_cast(unsigned int, __builtin_amdgcn_cvt_pkrtz(v1[0], v1[1]));
        pk.u[3] = __builtin_bit_cast(unsigned int, __builtin_amdgcn_cvt_pkrtz(v1[2], v1[3]));
        *(half8*)(AsB + dstb) = pk.v;
      }
      const _Float16* bs = BT + (size_t)(n0 + row) * 1024 + ko + colh;
      *(half8*)(BsB + dstb) = *(const half8*)bs;
    }
    __syncthreads();
#pragma unroll
    for (int kk = 0; kk < 64; kk += 32) {
      half8 af[4], bf[4];
#pragma unroll
      for (int mi = 0; mi < 4; ++mi) {
        const int row = wr + mi * 16 + (lane & 15);
        const int cb = (kk + (lane >> 4) * 8) * 2;
        af[mi] = *(const half8*)(AsB + row * 128 + (cb ^ ((row & 7) << 4)));
      }
#pragma unroll
      for (int ni = 0; ni < 4; ++ni) {
        const int row = wc + ni * 16 + (lane & 15);
        const int cb = (kk + (lane >> 4) * 8) * 2;
        bf[ni] = *(const half8*)(BsB + row * 128 + (cb ^ ((row & 7) << 4)));
      }
#pragma unroll
      for (int mi = 0; mi < 4; ++mi)
#pragma unroll
        for (int ni = 0; ni < 4; ++ni)
          acc[mi][ni] = MFMA16(af[mi], bf[ni], acc[mi][ni]);
    }
    __syncthreads();
  }

  // Epilogue. C/D layout: col = lane&15, row = (lane>>4)*4 + i
#pragma unroll
  for (int ni = 0; ni < 4; ++ni) {
    const int nn = n0 + wc + ni * 16 + (lane & 15);
    const float bvv = bias[nn];
#pragma unroll
    for (int mi = 0; mi < 4; ++mi) {
      floatx4 c = acc[mi][ni];
#pragma unroll
      for (int i = 0; i < 4; ++i) {
        const int mm = m0 + wr + mi * 16 + (lane >> 4) * 4 + i;
        float val = c[i] + bvv;
        if (OP == 0) val *= 0.1803368801111204f;   // (1/8) * log2(e)
        if (OP == 0 || OP == 1) {
          _Float16* o = (_Float16*)Cp;
          const size_t off =
              ((size_t)((mm >> 11) * 16 + (nn >> 6)) * 2048 + (mm & 2047)) * 64 + (nn & 63);
          o[off] = (_Float16)val;
        } else if (OP == 2) {
          _Float16* o = (_Float16*)Cp;
          // key index with bits 2<->3 swapped (k-axis permutation for PV)
          const int mmp = (mm & ~0xC) | ((mm & 4) << 1) | ((mm & 8) >> 1);
          const size_t off =
              ((size_t)((mm >> 11) * 16 + (nn >> 6)) * 64 + (nn & 63)) * 2048 + (mmp & 2047);
          o[off] = (_Float16)val;
        } else {
          float* o = (float*)Cp;
          o[(size_t)mm * 1024 + nn] = val;
        }
      }
    }
  }
}

// ---------------------------------------------------------------------------
// K3: flash attention, 32x32x16 MFMA, fixed-max in-register softmax.
// r15 structure (8 waves, 1 q-tile/wave, K/V LDS dbuf) + kk-SUBTILED LDS:
//   K: [kk][key][16 halfs]  (4 planes x 1KB)
//   V: [kk2][d][16 halfs]   (2 planes x 2KB)
// Each frag read is a CONTIGUOUS 1KB window (64 lanes x 16B = all 32 banks
// at the minimum 8 bank-cycles) -> provably conflict-free; was 4-way aliased
// (rows mod 8 shared banks under the row-XOR scheme) = the 8.4M counter.
// ---------------------------------------------------------------------------
__global__ __launch_bounds__(512) void attn_k(
    const _Float16* __restrict__ q_up, const _Float16* __restrict__ k_up,
    const _Float16* __restrict__ vT, const unsigned int* __restrict__ pmaskT,
    _Float16* __restrict__ ctx)
{
  const int tid = threadIdx.x;
  const int lane = tid & 63;
  const int wv = tid >> 6;                 // 0..7
  const int bid = blockIdx.x;
  const int xcd = bid & 7;
  const int slot = bid >> 3;
  const int bh = xcd * 8 + (slot & 7);
  const int qc = slot >> 3;
  const int b = bh >> 4;
  const int h = bh & 15;
  const int l31 = lane & 31;
  const int hi = lane >> 5;
  const int qw = qc * 256 + wv * 32;       // wave's 32 q-rows

  __shared__ __align__(16) _Float16 Kl[2][32 * 64];   // 2 x 4KB (4 planes/buf)
  __shared__ __align__(16) _Float16 Vl[2][64 * 32];   // 2 x 4KB (2 planes/buf)

  const _Float16* qb = q_up + ((size_t)bh * 2048 + qw) * 64;
  const _Float16* kb = k_up + (size_t)bh * 2048 * 64;
  const _Float16* vb = vT + (size_t)bh * 64 * 2048;
  const unsigned int* mbase = pmaskT + (size_t)(b * 64) * 2048 + qw + l31;

  // staging: waves 0-3 stage K, waves 4-7 stage V (256 thr x 16B each).
  // K: thread st -> key=st>>3, c=st&7 covers halfs [c*8, c*8+8) ->
  //    plane kk=c>>1, slot=c&1: byte = kk*1024 + key*32 + slot*16
  // V: thread st -> d=st>>2, seg=st&3 covers halfs [seg*8, seg*8+8) ->
  //    plane kk2=seg>>1, slot=seg&1: byte = kk2*2048 + d*32 + slot*16
  const bool isK = tid < 256;
  const int st = isK ? tid : tid - 256;
  const int vrow = st >> 2, vseg = st & 3;
  const int sOff = isK
      ? (((st & 7) >> 1) * 1024 + (st >> 3) * 32 + (st & 1) * 16)
      : ((vseg >> 1) * 2048 + vrow * 32 + (vseg & 1) * 16);
  const _Float16* gsrc = isK ? (kb + (size_t)st * 8)
                             : (vb + (size_t)vrow * 2048 + vseg * 8);
  const int gstride = isK ? 2048 : 32;     // halfs per 32-key tile
  char* Lbase = isK ? (char*)Kl : (char*)Vl;
  char* KB = (char*)Kl;
  char* VB = (char*)Vl;

  // Q B-frags (hoisted): col=q=l31, k = kk*16 + hi*8 + j
  half8 qf[4];
#pragma unroll
  for (int kk = 0; kk < 4; ++kk)
    qf[kk] = *(const half8*)(qb + (size_t)l31 * 64 + kk * 16 + hi * 8);

  floatx16 O[2];
#pragma unroll
  for (int dt = 0; dt < 2; ++dt)
#pragma unroll
    for (int r = 0; r < 16; ++r) O[dt][r] = 0.f;
  float lsum = 0.f;

  floatx16 zero16;
#pragma unroll
  for (int r = 0; r < 16; ++r) zero16[r] = 0.f;

  half8 stg;

  auto COMPUTE = [&](int buf, int t) {
    const unsigned int mw = mbase[(size_t)t * 2048];
    // K frags: plane kk, contiguous window: byte = kk*1024 + l31*32 + hi*16
    half8 kf[4];
#pragma unroll
    for (int kk = 0; kk < 4; ++kk)
      kf[kk] = *(const half8*)(KB + buf * 4096 + kk * 1024 + l31 * 32 + hi * 16);
    // V frags: plane kk2: byte = kk2*2048 + (dt*32+l31)*32 + hi*16
    half8 vf[2][2];
#pragma unroll
    for (int dt = 0; dt < 2; ++dt)
#pragma unroll
      for (int kk2 = 0; kk2 < 2; ++kk2)
        vf[dt][kk2] = *(const half8*)(VB + buf * 4096 + kk2 * 2048 +
                                      (dt * 32 + l31) * 32 + hi * 16);

    floatx16 s;
    __builtin_amdgcn_s_setprio(1);
    {
      floatx16 a;
      a = MFMA32(kf[0], qf[0], zero16);
      a = MFMA32(kf[1], qf[1], a);
      a = MFMA32(kf[2], qf[2], a);
      s = MFMA32(kf[3], qf[3], a);
    }
    __builtin_amdgcn_s_setprio(0);

    const unsigned int mh = mw >> (4 * hi);
    float e[16];
#pragma unroll
    for (int m = 0; m < 4; ++m) {
      const unsigned int bm = mh >> (8 * m);
#pragma unroll
      for (int j = 0; j < 4; ++j)
        e[4 * m + j] = ((bm >> j) & 1u) ? 0.f : __builtin_amdgcn_exp2f(s[4 * m + j]);
    }
    float u0 = (e[0] + e[1]) + (e[2] + e[3]);
    float u1 = (e[4] + e[5]) + (e[6] + e[7]);
    float u2 = (e[8] + e[9]) + (e[10] + e[11]);
    float u3 = (e[12] + e[13]) + (e[14] + e[15]);
    lsum += (u0 + u1) + (u2 + u3);

    union { half8 v; unsigned int u[4]; } p0, p1;
    p0.u[0] = __builtin_bit_cast(unsigned int, __builtin_amdgcn_cvt_pkrtz(e[0], e[1]));
    p0.u[1] = __builtin_bit_cast(unsigned int, __builtin_amdgcn_cvt_pkrtz(e[2], e[3]));
    p0.u[2] = __builtin_bit_cast(unsigned int, __builtin_amdgcn_cvt_pkrtz(e[4], e[5]));
    p0.u[3] = __builtin_bit_cast(unsigned int, __builtin_amdgcn_cvt_pkrtz(e[6], e[7]));
    p1.u[0] = __builtin_bit_cast(unsigned int, __builtin_amdgcn_cvt_pkrtz(e[8], e[9]));
    p1.u[1] = __builtin_bit_cast(unsigned int, __builtin_amdgcn_cvt_pkrtz(e[10], e[11]));
    p1.u[2] = __builtin_bit_cast(unsigned int, __builtin_amdgcn_cvt_pkrtz(e[12], e[13]));
    p1.u[3] = __builtin_bit_cast(unsigned int, __builtin_amdgcn_cvt_pkrtz(e[14], e[15]));
    __builtin_amdgcn_s_setprio(1);
#pragma unroll
    for (int dt = 0; dt < 2; ++dt) {
      O[dt] = MFMA32(vf[dt][0], p0.v, O[dt]);
      O[dt] = MFMA32(vf[dt][1], p1.v, O[dt]);
    }
    __builtin_amdgcn_s_setprio(0);
  };

  // prologue: stage tile 0 into buf0; fetch tile 1 into regs
  stg = *(const half8*)gsrc;
  *(half8*)(Lbase + sOff) = stg;
  stg = *(const half8*)(gsrc + gstride);
  __syncthreads();

#pragma unroll 1
  for (int t = 0; t < 64; t += 2) {
    {
      *(half8*)(Lbase + 4096 + sOff) = stg;
      const int tn = (t + 2 < 64) ? t + 2 : 0;
      stg = *(const half8*)(gsrc + (size_t)tn * gstride);
      COMPUTE(0, t);
      __syncthreads();
    }
    {
      *(half8*)(Lbase + sOff) = stg;
      const int tn = (t + 3 < 64) ? t + 3 : 0;
      stg = *(const half8*)(gsrc + (size_t)tn * gstride);
      COMPUTE(1, t + 1);
      __syncthreads();
    }
  }

  // Epilogue: cross-half lsum combine, then O^T write.
  {
    const float tot = lsum + __shfl_xor(lsum, 32);
    const float inv = 1.f / tot;
    const size_t rowb = ((size_t)(b * 2048 + qw + l31)) * 1024 + h * 64;
#pragma unroll
    for (int dt = 0; dt < 2; ++dt) {
#pragma unroll
      for (int m = 0; m < 4; ++m) {
        half4 w4;
        w4[0] = (_Float16)(O[dt][4 * m + 0] * inv);
        w4[1] = (_Float16)(O[dt][4 * m + 1] * inv);
        w4[2] = (_Float16)(O[dt][4 * m + 2] * inv);
        w4[3] = (_Float16)(O[dt][4 * m + 3] * inv);
        *(half4*)(ctx + rowb + dt * 32 + 8 * m + 4 * hi) = w4;
      }
    }
  }
}

// ---------------------------------------------------------------------------
// Launch. Workspace (fp16 elems): WT 4M | q_up 8M | k_up 8M | vT 8M | ctx 8M
// | pmaskT 2MB. Total ~74 MB.
// ---------------------------------------------------------------------------
extern "C" void kernel_launch(void* const* d_in, const int* in_sizes, int n_in,
                              void* d_out, int out_size, void* d_ws, size_t ws_size,
                              hipStream_t stream) {
  const float* key   = (const float*)d_in[0];
  const float* value = (const float*)d_in[1];
  const float* query = (const float*)d_in[2];
  const int*   mask  = (const int*)d_in[3];     // bool -> int32 per harness
  const float* Wq = (const float*)d_in[4];
  const float* bq = (const float*)d_in[5];
  const float* Wk = (const float*)d_in[6];
  const float* bk = (const float*)d_in[7];
  const float* Wv = (const float*)d_in[8];
  const float* bv = (const float*)d_in[9];
  const float* Wo = (const float*)d_in[10];
  const float* bo = (const float*)d_in[11];

  _Float16* wsp = (_Float16*)d_ws;
  _Float16* WT   = wsp;
  _Float16* q_up = wsp + (size_t)4 * 1024 * 1024;
  _Float16* k_up = q_up + (size_t)8192 * 1024;
  _Float16* vT   = k_up + (size_t)8192 * 1024;
  _Float16* ctx  = vT + (size_t)8192 * 1024;
  unsigned int* pmaskT = (unsigned int*)(ctx + (size_t)8192 * 1024);

  maskpack<<<dim3(2048), 256, 0, stream>>>(mask, pmaskT);
  wconv<<<dim3(32, 32, 4), 256, 0, stream>>>(Wq, Wk, Wv, Wo, WT);
  gemm_k<0><<<dim3(64, 8), 256, 0, stream>>>(query, WT, bq, q_up);
  gemm_k<1><<<dim3(64, 8), 256, 0, stream>>>(key, WT + (size_t)1024 * 1024, bk, k_up);
  gemm_k<2><<<dim3(64, 8), 256, 0, stream>>>(value, WT + (size_t)2 * 1024 * 1024, bv, vT);
  attn_k<<<dim3(512), 512, 0, stream>>>(q_up, k_up, vT, pmaskT, ctx);
  gemm_k<3><<<dim3(64, 8), 256, 0, stream>>>(ctx, WT + (size_t)3 * 1024 * 1024, bo, (float*)d_out);
}